// Round 4
// baseline (275.760 us; speedup 1.0000x reference)
//
#include <hip/hip_runtime.h>
#include <math.h>

#define B_  64
#define L_  2048
#define DM  12
#define DI  24
#define DS  16
#define DC  4
#define DTR 1
#define T_  (B_ * L_)        // 131072 tokens
#define NCHUNK 16
#define CHUNK  128           // L_ / NCHUNK

// ---------------- ws layout (floats) — total 19,530,240 (same as passing rounds) ----
// dxT : B*DI*2L   {delta, xi} interleaved pairs, d-major rows     6,291,456
// zsT : B*DI*L    silu(z), d-major                                3,145,728
// BT  : B*DS*L    n-major                                         2,097,152
// CT  : B*DS*L    n-major                                         2,097,152
// yT  : B*DI*L    gated scan output, d-major                      3,145,728
// xfT : B*DM*L    |FFT(x)|, dm-major                              1,572,864
// P,H,H0 : 3 * B*DI*NCHUNK*DS                                     1,179,648
// part: 512

__device__ __forceinline__ float siluf(float v)  { return v / (1.0f + expf(-v)); }
__device__ __forceinline__ float softplusf(float v) {
    if (v > 20.0f)  return v;
    if (v < -20.0f) return expf(v);
    return log1pf(expf(v));
}
__device__ __forceinline__ float geluf(float v) {
    return 0.5f * v * (1.0f + erff(v * 0.70710678118654752440f));
}
__device__ __forceinline__ float eluf(float v) { return v > 0.0f ? v : expf(v) - 1.0f; }

// 16-lane sum via DPP (quad_perm xor1, xor2, row_ror:4, row_ror:8) — no DS pipe.
#define DPP_ADD(p, ctrl) \
    (p) += __int_as_float(__builtin_amdgcn_update_dpp(0, __float_as_int(p), (ctrl), 0xF, 0xF, true))

// ============ K1: in_proj + conv + silu + x_proj + delta, TRANSPOSED outputs ============
__global__ __launch_bounds__(256) void k_proj(
    const float* __restrict__ x, const float* __restrict__ w_in,
    const float* __restrict__ conv_w, const float* __restrict__ conv_b,
    const float* __restrict__ xproj_w, const float* __restrict__ dt_w,
    const float* __restrict__ dt_b,
    float* __restrict__ dxT, float* __restrict__ zsT,
    float* __restrict__ BT, float* __restrict__ CT)
{
    __shared__ float s_conv[256 + 3][DI + 1];
    __shared__ float s_t[6192];            // transpose tile (24.8 KB), reused 5x
    const int tid = threadIdx.x;
    const int b   = blockIdx.x >> 3;
    const int l0  = (blockIdx.x & 7) << 8;
    const int l   = l0 + tid;
    const int t   = b * L_ + l;

    float xv[DM];
    *(float4*)&xv[0] = *(const float4*)&x[t * DM + 0];
    *(float4*)&xv[4] = *(const float4*)&x[t * DM + 4];
    *(float4*)&xv[8] = *(const float4*)&x[t * DM + 8];

    // pre-conv xi -> s_conv; silu(z) -> s_t (zs tile, stride 258)
#pragma unroll
    for (int e = 0; e < DI; ++e) {
        float acc = 0.0f, accz = 0.0f;
#pragma unroll
        for (int d = 0; d < DM; ++d) {
            acc  += xv[d] * w_in[e * DM + d];
            accz += xv[d] * w_in[(DI + e) * DM + d];
        }
        s_conv[tid + 3][e] = acc;
        s_t[e * 258 + tid] = siluf(accz);
    }
    if (tid < 3) {
        const int lh = l0 - 3 + tid;
        if (lh < 0) {
            for (int e = 0; e < DI; ++e) s_conv[tid][e] = 0.0f;
        } else {
            const int th = b * L_ + lh;
            float xh[DM];
            for (int d = 0; d < DM; ++d) xh[d] = x[th * DM + d];
            for (int e = 0; e < DI; ++e) {
                float acc = 0.0f;
                for (int d = 0; d < DM; ++d) acc += xh[d] * w_in[e * DM + d];
                s_conv[tid][e] = acc;
            }
        }
    }
    __syncthreads();

    // zs rows out (coalesced)
#pragma unroll
    for (int r = 0; r < DI; ++r)
        zsT[(size_t)(b * DI + r) * L_ + l0 + tid] = s_t[r * 258 + tid];

    // conv + silu
    float xi[DI];
#pragma unroll
    for (int dch = 0; dch < DI; ++dch) {
        float acc = conv_b[dch];
#pragma unroll
        for (int k = 0; k < DC; ++k) acc += s_conv[tid + k][dch] * conv_w[dch * DC + k];
        xi[dch] = siluf(acc);
    }

    float dt = 0.0f;
#pragma unroll
    for (int d = 0; d < DI; ++d) dt += xi[d] * xproj_w[d];
    float Bv[DS], Cv[DS];
#pragma unroll
    for (int e = 0; e < DS; ++e) {
        float accB = 0.0f, accC = 0.0f;
#pragma unroll
        for (int d = 0; d < DI; ++d) {
            accB += xi[d] * xproj_w[(1 + e) * DI + d];
            accC += xi[d] * xproj_w[(1 + DS + e) * DI + d];
        }
        Bv[e] = accB;
        Cv[e] = accC;
    }
    float de[DI];
#pragma unroll
    for (int d = 0; d < DI; ++d) de[d] = softplusf(dt * dt_w[d] + dt_b[d]);

    __syncthreads();   // zs tile fully read
    // dx pairs, low half (rows 0..11), stride 514
#pragma unroll
    for (int r = 0; r < 12; ++r) {
        s_t[r * 514 + 2 * tid]     = de[r];
        s_t[r * 514 + 2 * tid + 1] = xi[r];
    }
    __syncthreads();
#pragma unroll
    for (int r = 0; r < 12; ++r)
        *(float2*)&dxT[(size_t)(b * DI + r) * 2 * L_ + 2 * (l0 + tid)] =
            *(float2*)&s_t[r * 514 + 2 * tid];
    __syncthreads();
    // dx pairs, high half (rows 12..23)
#pragma unroll
    for (int r = 0; r < 12; ++r) {
        s_t[r * 514 + 2 * tid]     = de[12 + r];
        s_t[r * 514 + 2 * tid + 1] = xi[12 + r];
    }
    __syncthreads();
#pragma unroll
    for (int r = 0; r < 12; ++r)
        *(float2*)&dxT[(size_t)(b * DI + 12 + r) * 2 * L_ + 2 * (l0 + tid)] =
            *(float2*)&s_t[r * 514 + 2 * tid];
    __syncthreads();
    // B
#pragma unroll
    for (int r = 0; r < DS; ++r) s_t[r * 258 + tid] = Bv[r];
    __syncthreads();
#pragma unroll
    for (int r = 0; r < DS; ++r)
        BT[(size_t)(b * DS + r) * L_ + l0 + tid] = s_t[r * 258 + tid];
    __syncthreads();
    // C
#pragma unroll
    for (int r = 0; r < DS; ++r) s_t[r * 258 + tid] = Cv[r];
    __syncthreads();
#pragma unroll
    for (int r = 0; r < DS; ++r)
        CT[(size_t)(b * DS + r) * L_ + l0 + tid] = s_t[r * 258 + tid];
}

// ============ S1: per-chunk local scan — no LDS, float4 register streaming ============
__global__ __launch_bounds__(384) void k_scan1(
    const float* __restrict__ dxT, const float* __restrict__ BT,
    const float* __restrict__ A_log,
    float* __restrict__ P, float* __restrict__ H)
{
    const int tid = threadIdx.x;            // = d*16 + n
    const int d   = tid >> 4;
    const int n   = tid & 15;
    const int b   = blockIdx.x / NCHUNK;
    const int c   = blockIdx.x % NCHUNK;
    const int c0  = c * CHUNK;
    const float An = -expf(A_log[tid]);

    const float* pdx = dxT + (size_t)(b * DI + d) * 2 * L_ + 2 * c0;
    const float* pB  = BT  + (size_t)(b * DS + n) * L_ + c0;

    float h = 0.0f, prod = 1.0f;
#pragma unroll 4
    for (int i = 0; i < CHUNK; i += 2) {
        const float4 dx = *(const float4*)&pdx[2 * i];
        const float2 Bv = *(const float2*)&pB[i];
        float a = expf(dx.x * An);
        h = a * h + dx.x * dx.y * Bv.x;
        prod *= a;
        a = expf(dx.z * An);
        h = a * h + dx.z * dx.w * Bv.y;
        prod *= a;
    }
    const int u = ((b * DI + d) * NCHUNK + c) * DS + n;
    P[u] = prod;
    H[u] = h;
}

// ============ S2: combine chunk summaries ============
__global__ __launch_bounds__(256) void k_scan2(
    const float* __restrict__ P, const float* __restrict__ H, float* __restrict__ H0)
{
    const int idx  = blockIdx.x * 256 + threadIdx.x;  // 24576 = (b*DI+d)*16 + n
    const int n    = idx & 15;
    const int rest = idx >> 4;
    float Hc = 0.0f;
    const int base = rest * NCHUNK * DS + n;
    for (int c = 0; c < NCHUNK; ++c) {
        const int u = base + c * DS;
        H0[u] = Hc;
        Hc = P[u] * Hc + H[u];
    }
}

// ============ S3: replay + gate, DPP n-reduction, direct yT stores ============
__global__ __launch_bounds__(384) void k_scan3(
    const float* __restrict__ dxT, const float* __restrict__ BT,
    const float* __restrict__ CT, const float* __restrict__ zsT,
    const float* __restrict__ Dp, const float* __restrict__ H0,
    const float* __restrict__ A_log, float* __restrict__ yT)
{
    const int tid = threadIdx.x;
    const int d   = tid >> 4;
    const int n   = tid & 15;
    const int b   = blockIdx.x / NCHUNK;
    const int c   = blockIdx.x % NCHUNK;
    const int c0  = c * CHUNK;
    const float An  = -expf(A_log[tid]);
    const float Dpd = Dp[d];

    const float* pdx = dxT + (size_t)(b * DI + d) * 2 * L_ + 2 * c0;
    const float* pB  = BT  + (size_t)(b * DS + n) * L_ + c0;
    const float* pC  = CT  + (size_t)(b * DS + n) * L_ + c0;
    const float* pz  = zsT + (size_t)(b * DI + d) * L_ + c0;
    float*       py  = yT  + (size_t)(b * DI + d) * L_ + c0;

    const int u = ((b * DI + d) * NCHUNK + c) * DS + n;
    float h = H0[u];

#pragma unroll 4
    for (int i = 0; i < CHUNK; i += 2) {
        const float4 dx = *(const float4*)&pdx[2 * i];
        const float2 Bv = *(const float2*)&pB[i];
        const float2 Cv = *(const float2*)&pC[i];
        {
            const float a = expf(dx.x * An);
            h = a * h + dx.x * dx.y * Bv.x;
            float p = h * Cv.x;
            DPP_ADD(p, 0xB1);    // xor 1 (quad_perm 1,0,3,2)
            DPP_ADD(p, 0x4E);    // xor 2 (quad_perm 2,3,0,1)
            DPP_ADD(p, 0x124);   // row_ror:4
            DPP_ADD(p, 0x128);   // row_ror:8
            if (n == 0) py[i] = (p + dx.y * Dpd) * pz[i];
        }
        {
            const float a = expf(dx.z * An);
            h = a * h + dx.z * dx.w * Bv.y;
            float p = h * Cv.y;
            DPP_ADD(p, 0xB1);
            DPP_ADD(p, 0x4E);
            DPP_ADD(p, 0x124);
            DPP_ADD(p, 0x128);
            if (n == 0) py[i + 1] = (p + dx.w * Dpd) * pz[i + 1];
        }
    }
}

// ============ K5: two real FFTs per complex 2048-pt FFT, xfT coalesced out ============
__global__ __launch_bounds__(256) void k_fft(
    const float* __restrict__ x, float* __restrict__ xfT)
{
    __shared__ float re[2048], im[2048], twr[1024], twi[1024];
    const int tid = threadIdx.x;
    const int b   = blockIdx.x / (DM / 2);
    const int p   = blockIdx.x % (DM / 2);   // channel pair (2p, 2p+1)
    for (int j = tid; j < 1024; j += 256) {
        const float ang = -6.283185307179586f * (float)j * (1.0f / 2048.0f);
        float s, c;
        sincosf(ang, &s, &c);
        twr[j] = c; twi[j] = s;
    }
    for (int i = tid; i < 2048; i += 256) {
        const int r = (int)(__brev((unsigned)i) >> 21);
        const float2 v = *(const float2*)&x[(size_t)(b * L_ + i) * DM + 2 * p];
        re[r] = v.x;
        im[r] = v.y;
    }
    __syncthreads();
    for (int s = 1; s <= 11; ++s) {
        const int half  = 1 << (s - 1);
        const int tstep = 2048 >> s;
        for (int i = tid; i < 1024; i += 256) {
            const int j   = i & (half - 1);
            const int grp = i >> (s - 1);
            const int pos = (grp << s) + j;
            const float wr = twr[j * tstep], wi = twi[j * tstep];
            const float ar = re[pos + half], ai = im[pos + half];
            const float vr = wr * ar - wi * ai;
            const float vi = wr * ai + wi * ar;
            const float ur = re[pos], ui = im[pos];
            re[pos] = ur + vr;          im[pos] = ui + vi;
            re[pos + half] = ur - vr;   im[pos + half] = ui - vi;
        }
        __syncthreads();
    }
    // unpack: X1 = (Z[k]+conj(Z[N-k]))/2, X2 = (Z[k]-conj(Z[N-k]))/(2i)
    float* row1 = xfT + (size_t)(b * DM + 2 * p) * L_;
    float* row2 = row1 + L_;
    for (int k = tid; k < 2048; k += 256) {
        const int nk = (2048 - k) & 2047;
        const float zr = re[k],  zi = im[k];
        const float qr = re[nk], qi = im[nk];
        const float e1r = zr + qr, e1i = zi - qi;
        const float e2r = zr - qr, e2i = zi + qi;
        row1[k] = 0.5f * sqrtf(e1r * e1r + e1i * e1i);
        row2[k] = 0.5f * sqrtf(e2r * e2r + e2i * e2i);
    }
}

// ============ K6: out_proj + LN + FFN + LN + CNN + head + partial sum ============
__global__ __launch_bounds__(256) void k_tail(
    const float* __restrict__ yT, const float* __restrict__ xfT,
    const float* __restrict__ out_w,
    const float* __restrict__ ln1_g, const float* __restrict__ ln1_b,
    const float* __restrict__ w1, const float* __restrict__ b1,
    const float* __restrict__ w2, const float* __restrict__ b2,
    const float* __restrict__ lng, const float* __restrict__ lnb,
    const float* __restrict__ cnn_w, const float* __restrict__ cnn_b,
    const float* __restrict__ l1w, const float* __restrict__ l1b,
    const float* __restrict__ l2w, const float* __restrict__ l2b,
    const float* __restrict__ l3w, const float* __restrict__ l3b,
    float* __restrict__ part)
{
    const int tid = threadIdx.x;
    const int b   = blockIdx.x >> 3;
    const int l   = ((blockIdx.x & 7) << 8) + tid;

    float y[DI];
#pragma unroll
    for (int e = 0; e < DI; ++e) y[e] = yT[(size_t)(b * DI + e) * L_ + l];

    float m[DM];
#pragma unroll
    for (int j = 0; j < DM; ++j) {
        float acc = 0.0f;
#pragma unroll
        for (int e = 0; e < DI; ++e) acc += y[e] * out_w[j * DI + e];
        m[j] = acc;
    }
    float mean = 0.0f;
#pragma unroll
    for (int j = 0; j < DM; ++j) mean += m[j];
    mean *= (1.0f / DM);
    float var = 0.0f;
#pragma unroll
    for (int j = 0; j < DM; ++j) { const float dv = m[j] - mean; var += dv * dv; }
    var *= (1.0f / DM);
    const float inv1 = rsqrtf(var + 1e-12f);
    float h[DM];
#pragma unroll
    for (int j = 0; j < DM; ++j) h[j] = (m[j] - mean) * inv1 * ln1_g[j] + ln1_b[j];

    float ff[4 * DM];
#pragma unroll
    for (int e = 0; e < 4 * DM; ++e) {
        float acc = b1[e];
#pragma unroll
        for (int j = 0; j < DM; ++j) acc += h[j] * w1[e * DM + j];
        ff[e] = geluf(acc);
    }
    float f2[DM];
#pragma unroll
    for (int j = 0; j < DM; ++j) {
        float acc = b2[j];
#pragma unroll
        for (int e = 0; e < 4 * DM; ++e) acc += ff[e] * w2[j * (4 * DM) + e];
        f2[j] = acc + h[j];
    }
    mean = 0.0f;
#pragma unroll
    for (int j = 0; j < DM; ++j) mean += f2[j];
    mean *= (1.0f / DM);
    var = 0.0f;
#pragma unroll
    for (int j = 0; j < DM; ++j) { const float dv = f2[j] - mean; var += dv * dv; }
    var *= (1.0f / DM);
    const float inv2 = rsqrtf(var + 1e-12f);
    float xm[DM];
#pragma unroll
    for (int j = 0; j < DM; ++j) xm[j] = (f2[j] - mean) * inv2 * lng[j] + lnb[j];

    float xfm[DM], xf0[DM], xfp[DM];
#pragma unroll
    for (int i = 0; i < DM; ++i) {
        const float* row = xfT + (size_t)(b * DM + i) * L_;
        xfm[i] = (l == 0)      ? 0.0f : row[l - 1];
        xf0[i] = row[l];
        xfp[i] = (l == L_ - 1) ? 0.0f : row[l + 1];
    }
    float xc[DM];
#pragma unroll
    for (int o = 0; o < DM; ++o) {
        float acc = cnn_b[o];
#pragma unroll
        for (int i = 0; i < DM; ++i) {
            const int wb = (o * DM + i) * 3;
            acc += xfm[i] * cnn_w[wb] + xf0[i] * cnn_w[wb + 1] + xfp[i] * cnn_w[wb + 2];
        }
        xc[o] = acc;
    }

    float o1[DM];
#pragma unroll
    for (int d = 0; d < DM; ++d) {
        float acc = l1b[d];
#pragma unroll
        for (int e = 0; e < DM; ++e) acc += xm[e] * l1w[d * (2 * DM) + e];
#pragma unroll
        for (int e = 0; e < DM; ++e) acc += xc[e] * l1w[d * (2 * DM) + DM + e];
        o1[d] = eluf(acc);
    }
    float o2[20];
#pragma unroll
    for (int e = 0; e < 20; ++e) {
        float acc = l2b[e];
#pragma unroll
        for (int d = 0; d < DM; ++d) acc += o1[d] * l2w[e * DM + d];
        o2[e] = acc;
    }
    float o3 = l3b[0];
#pragma unroll
    for (int e = 0; e < 20; ++e) o3 += o2[e] * l3w[e];

    __shared__ float sred[256];
    sred[tid] = o3;
    __syncthreads();
    for (int s = 128; s > 0; s >>= 1) {
        if (tid < s) sred[tid] += sred[tid + s];
        __syncthreads();
    }
    if (tid == 0) part[blockIdx.x] = sred[0];
}

// ============ K7: final per-batch mean + sigmoid ============
__global__ void k_final(const float* __restrict__ part, float* __restrict__ out)
{
    const int b = threadIdx.x;
    if (b < B_) {
        float s = 0.0f;
        for (int i = 0; i < 8; ++i) s += part[b * 8 + i];
        s *= (1.0f / (float)L_);
        out[b] = 1.0f / (1.0f + expf(-s));
    }
}

extern "C" void kernel_launch(void* const* d_in, const int* in_sizes, int n_in,
                              void* d_out, int out_size, void* d_ws, size_t ws_size,
                              hipStream_t stream)
{
    const float* x        = (const float*)d_in[0];
    const float* in_w     = (const float*)d_in[1];
    const float* conv_w   = (const float*)d_in[2];
    const float* conv_b   = (const float*)d_in[3];
    const float* xproj_w  = (const float*)d_in[4];
    const float* dt_w     = (const float*)d_in[5];
    const float* dt_b     = (const float*)d_in[6];
    const float* A_log    = (const float*)d_in[7];
    const float* Dp       = (const float*)d_in[8];
    const float* out_w    = (const float*)d_in[9];
    const float* ln1_g    = (const float*)d_in[10];
    const float* ln1_b    = (const float*)d_in[11];
    const float* ffn_w1   = (const float*)d_in[12];
    const float* ffn_b1   = (const float*)d_in[13];
    const float* ffn_w2   = (const float*)d_in[14];
    const float* ffn_b2   = (const float*)d_in[15];
    const float* ffn_ln_g = (const float*)d_in[16];
    const float* ffn_ln_b = (const float*)d_in[17];
    const float* cnn_w    = (const float*)d_in[18];
    const float* cnn_b    = (const float*)d_in[19];
    const float* l1w      = (const float*)d_in[20];
    const float* l1b      = (const float*)d_in[21];
    const float* l2w      = (const float*)d_in[22];
    const float* l2b      = (const float*)d_in[23];
    const float* l3w      = (const float*)d_in[24];
    const float* l3b      = (const float*)d_in[25];
    float* out = (float*)d_out;

    float* ws = (float*)d_ws;
    const size_t nDX = (size_t)B_ * DI * 2 * L_;
    const size_t nDL = (size_t)B_ * DI * L_;
    const size_t nNL = (size_t)B_ * DS * L_;
    const size_t nML = (size_t)B_ * DM * L_;
    const size_t nU  = (size_t)B_ * DI * NCHUNK * DS;
    float* w_dxT = ws;
    float* w_zsT = w_dxT + nDX;
    float* w_BT  = w_zsT + nDL;
    float* w_CT  = w_BT + nNL;
    float* w_yT  = w_CT + nNL;
    float* w_xfT = w_yT + nDL;
    float* w_P   = w_xfT + nML;
    float* w_H   = w_P + nU;
    float* w_H0  = w_H + nU;
    float* w_part= w_H0 + nU;

    k_proj<<<512, 256, 0, stream>>>(x, in_w, conv_w, conv_b, xproj_w, dt_w, dt_b,
                                    w_dxT, w_zsT, w_BT, w_CT);
    k_fft<<<B_ * (DM / 2), 256, 0, stream>>>(x, w_xfT);
    k_scan1<<<B_ * NCHUNK, 384, 0, stream>>>(w_dxT, w_BT, A_log, w_P, w_H);
    k_scan2<<<96, 256, 0, stream>>>(w_P, w_H, w_H0);
    k_scan3<<<B_ * NCHUNK, 384, 0, stream>>>(w_dxT, w_BT, w_CT, w_zsT, Dp,
                                             w_H0, A_log, w_yT);
    k_tail<<<512, 256, 0, stream>>>(w_yT, w_xfT, out_w,
                                    ln1_g, ln1_b, ffn_w1, ffn_b1, ffn_w2, ffn_b2,
                                    ffn_ln_g, ffn_ln_b, cnn_w, cnn_b,
                                    l1w, l1b, l2w, l2b, l3w, l3b, w_part);
    k_final<<<1, 64, 0, stream>>>(w_part, out);
}

// Round 5
// 220.323 us; speedup vs baseline: 1.2516x; 1.2516x over previous
//
#include <hip/hip_runtime.h>
#include <math.h>

#define B_  64
#define L_  2048
#define DM  12
#define DI  24
#define DS  16
#define DC  4
#define DTR 1
#define T_  (B_ * L_)        // 131072 tokens
#define NCHUNK 32
#define CHUNK  64            // L_ / NCHUNK
#define CPB    4             // chunks per scan block

// ---------------- ws layout (floats) — total 19,137,024 < proven 19,530,240 ----
// delta : T*DI   3,145,728
// xi    : T*DI   3,145,728
// zs    : T*DI   3,145,728
// y     : T*DI   3,145,728   (gated scan output, t-major)
// Bm    : T*DS   2,097,152
// Cm    : T*DS   2,097,152
// P     : B*DI*NCHUNK*DS   786,432   \ aliased as xf (B*DM*L = 1,572,864)
// H     : B*DI*NCHUNK*DS   786,432   /  after scan2 completes
// H0    : B*DI*NCHUNK*DS   786,432
// part  : 512

__device__ __forceinline__ float siluf(float v)  { return v / (1.0f + expf(-v)); }
__device__ __forceinline__ float softplusf(float v) {
    if (v > 20.0f)  return v;
    if (v < -20.0f) return expf(v);
    return log1pf(expf(v));
}
__device__ __forceinline__ float geluf(float v) {
    return 0.5f * v * (1.0f + erff(v * 0.70710678118654752440f));
}
__device__ __forceinline__ float eluf(float v) { return v > 0.0f ? v : expf(v) - 1.0f; }

// quad (4-lane) sum via DPP: quad_perm{1,0,3,2}=0xB1, quad_perm{2,3,0,1}=0x4E
#define DPP_ADD(p, ctrl) \
    (p) += __int_as_float(__builtin_amdgcn_update_dpp(0, __float_as_int(p), (ctrl), 0xF, 0xF, true))

// ============ K1: in_proj + depthwise causal conv + silu + x_proj + delta ============
__global__ __launch_bounds__(256) void k_proj(
    const float* __restrict__ x, const float* __restrict__ w_in,
    const float* __restrict__ conv_w, const float* __restrict__ conv_b,
    const float* __restrict__ xproj_w, const float* __restrict__ dt_w,
    const float* __restrict__ dt_b,
    float* __restrict__ xi_out, float* __restrict__ zs_out,
    float* __restrict__ delta_out, float* __restrict__ Bm_out,
    float* __restrict__ Cm_out)
{
    __shared__ float s_xi[256 + 3][DI + 1];
    const int tid = threadIdx.x;
    const int b   = blockIdx.x >> 3;
    const int l0  = (blockIdx.x & 7) << 8;
    const int l   = l0 + tid;
    const int t   = b * L_ + l;

    float xv[DM];
    *(float4*)&xv[0] = *(const float4*)&x[t * DM + 0];
    *(float4*)&xv[4] = *(const float4*)&x[t * DM + 4];
    *(float4*)&xv[8] = *(const float4*)&x[t * DM + 8];

#pragma unroll
    for (int e = 0; e < DI; ++e) {
        float acc = 0.0f;
#pragma unroll
        for (int d = 0; d < DM; ++d) acc += xv[d] * w_in[(DI + e) * DM + d];
        zs_out[t * DI + e] = siluf(acc);
    }
#pragma unroll
    for (int e = 0; e < DI; ++e) {
        float acc = 0.0f;
#pragma unroll
        for (int d = 0; d < DM; ++d) acc += xv[d] * w_in[e * DM + d];
        s_xi[tid + 3][e] = acc;
    }
    if (tid < 3) {
        const int lh = l0 - 3 + tid;
        if (lh < 0) {
            for (int e = 0; e < DI; ++e) s_xi[tid][e] = 0.0f;
        } else {
            const int th = b * L_ + lh;
            float xh[DM];
            for (int d = 0; d < DM; ++d) xh[d] = x[th * DM + d];
            for (int e = 0; e < DI; ++e) {
                float acc = 0.0f;
                for (int d = 0; d < DM; ++d) acc += xh[d] * w_in[e * DM + d];
                s_xi[tid][e] = acc;
            }
        }
    }
    __syncthreads();

    float xi[DI];
#pragma unroll
    for (int dch = 0; dch < DI; ++dch) {
        float acc = conv_b[dch];
#pragma unroll
        for (int k = 0; k < DC; ++k) acc += s_xi[tid + k][dch] * conv_w[dch * DC + k];
        xi[dch] = siluf(acc);
        xi_out[t * DI + dch] = xi[dch];
    }

    float dt = 0.0f;
#pragma unroll
    for (int d = 0; d < DI; ++d) dt += xi[d] * xproj_w[d];
#pragma unroll
    for (int e = 0; e < DS; ++e) {
        float accB = 0.0f, accC = 0.0f;
#pragma unroll
        for (int d = 0; d < DI; ++d) {
            accB += xi[d] * xproj_w[(1 + e) * DI + d];
            accC += xi[d] * xproj_w[(1 + DS + e) * DI + d];
        }
        Bm_out[t * DS + e] = accB;
        Cm_out[t * DS + e] = accC;
    }
#pragma unroll
    for (int d = 0; d < DI; ++d)
        delta_out[t * DI + d] = softplusf(dt * dt_w[d] + dt_b[d]);
}

// ============ S1: local chunk scan — thread owns (b,d,c,n-quad), 4 h's in regs ============
__global__ __launch_bounds__(384) void k_scan1(
    const float* __restrict__ delta, const float* __restrict__ xi,
    const float* __restrict__ Bm, const float* __restrict__ A_log,
    float* __restrict__ P, float* __restrict__ H)
{
    const int tid = threadIdx.x;          // (cl*24 + d)*4 + q
    const int q   = tid & 3;
    const int g   = tid >> 2;
    const int d   = g % DI;
    const int cl  = g / DI;
    const int b   = blockIdx.x >> 3;      // NCHUNK/CPB = 8 blocks per b
    const int c   = ((blockIdx.x & 7) << 2) + cl;
    const int t0  = b * L_ + c * CHUNK;

    float An[4], h[4] = {0,0,0,0}, prod[4] = {1,1,1,1};
#pragma unroll
    for (int j = 0; j < 4; ++j) An[j] = -expf(A_log[d * DS + 4 * q + j]);

    const float* pD = delta + (size_t)t0 * DI + d;
    const float* pX = xi    + (size_t)t0 * DI + d;
    const float* pB = Bm    + (size_t)t0 * DS + 4 * q;

#pragma unroll 4
    for (int i = 0; i < CHUNK; ++i) {
        const float del = pD[i * DI];
        const float u   = del * pX[i * DI];
        const float4 Bv = *(const float4*)&pB[i * DS];
#pragma unroll
        for (int j = 0; j < 4; ++j) {
            const float a = expf(del * An[j]);
            h[j] = a * h[j] + u * (&Bv.x)[j];
            prod[j] *= a;
        }
    }
    const int u4 = ((b * DI + d) * NCHUNK + c) * DS + 4 * q;
    *(float4*)&P[u4] = make_float4(prod[0], prod[1], prod[2], prod[3]);
    *(float4*)&H[u4] = make_float4(h[0], h[1], h[2], h[3]);
}

// ============ S2: combine chunk summaries (thread = (b,d,n)) ============
__global__ __launch_bounds__(256) void k_scan2(
    const float* __restrict__ P, const float* __restrict__ H, float* __restrict__ H0)
{
    const int idx  = blockIdx.x * 256 + threadIdx.x;  // 24576 = (b*DI+d)*16 + n
    const int n    = idx & 15;
    const int rest = idx >> 4;
    float Hc = 0.0f;
    const int base = rest * NCHUNK * DS + n;
    for (int c = 0; c < NCHUNK; ++c) {
        const int u = base + c * DS;
        H0[u] = Hc;
        Hc = P[u] * Hc + H[u];
    }
}

// ============ S3: replay with h0 + fused gate, y stored t-major ============
__global__ __launch_bounds__(384) void k_scan3(
    const float* __restrict__ delta, const float* __restrict__ xi,
    const float* __restrict__ Bm, const float* __restrict__ Cm,
    const float* __restrict__ zs, const float* __restrict__ Dp,
    const float* __restrict__ H0, const float* __restrict__ A_log,
    float* __restrict__ y_out)
{
    const int tid = threadIdx.x;
    const int q   = tid & 3;
    const int g   = tid >> 2;
    const int d   = g % DI;
    const int cl  = g / DI;
    const int b   = blockIdx.x >> 3;
    const int c   = ((blockIdx.x & 7) << 2) + cl;
    const int t0  = b * L_ + c * CHUNK;

    float An[4];
#pragma unroll
    for (int j = 0; j < 4; ++j) An[j] = -expf(A_log[d * DS + 4 * q + j]);
    const float Dpd = Dp[d];

    const int u4 = ((b * DI + d) * NCHUNK + c) * DS + 4 * q;
    const float4 h0 = *(const float4*)&H0[u4];
    float h[4] = {h0.x, h0.y, h0.z, h0.w};

    const float* pD = delta + (size_t)t0 * DI + d;
    const float* pX = xi    + (size_t)t0 * DI + d;
    const float* pZ = zs    + (size_t)t0 * DI + d;
    const float* pB = Bm    + (size_t)t0 * DS + 4 * q;
    const float* pC = Cm    + (size_t)t0 * DS + 4 * q;
    float*       pY = y_out + (size_t)t0 * DI + d;

#pragma unroll 4
    for (int i = 0; i < CHUNK; ++i) {
        const float del = pD[i * DI];
        const float xiv = pX[i * DI];
        const float u   = del * xiv;
        const float4 Bv = *(const float4*)&pB[i * DS];
        const float4 Cv = *(const float4*)&pC[i * DS];
        float p = 0.0f;
#pragma unroll
        for (int j = 0; j < 4; ++j) {
            const float a = expf(del * An[j]);
            h[j] = a * h[j] + u * (&Bv.x)[j];
            p += h[j] * (&Cv.x)[j];
        }
        DPP_ADD(p, 0xB1);   // + lane^1 (within quad)
        DPP_ADD(p, 0x4E);   // + lane^2 (within quad)
        if (q == 0) pY[i * DI] = (p + xiv * Dpd) * pZ[i * DI];
    }
}

// ============ K5: two real FFTs per complex 2048-pt FFT, xfT (dm-major) out ============
__global__ __launch_bounds__(256) void k_fft(
    const float* __restrict__ x, float* __restrict__ xfT)
{
    __shared__ float re[2048], im[2048], twr[1024], twi[1024];
    const int tid = threadIdx.x;
    const int b   = blockIdx.x / (DM / 2);
    const int p   = blockIdx.x % (DM / 2);   // channel pair (2p, 2p+1)
    for (int j = tid; j < 1024; j += 256) {
        const float ang = -6.283185307179586f * (float)j * (1.0f / 2048.0f);
        float s, c;
        sincosf(ang, &s, &c);
        twr[j] = c; twi[j] = s;
    }
    for (int i = tid; i < 2048; i += 256) {
        const int r = (int)(__brev((unsigned)i) >> 21);
        const float2 v = *(const float2*)&x[(size_t)(b * L_ + i) * DM + 2 * p];
        re[r] = v.x;
        im[r] = v.y;
    }
    __syncthreads();
    for (int s = 1; s <= 11; ++s) {
        const int half  = 1 << (s - 1);
        const int tstep = 2048 >> s;
        for (int i = tid; i < 1024; i += 256) {
            const int j   = i & (half - 1);
            const int grp = i >> (s - 1);
            const int pos = (grp << s) + j;
            const float wr = twr[j * tstep], wi = twi[j * tstep];
            const float ar = re[pos + half], ai = im[pos + half];
            const float vr = wr * ar - wi * ai;
            const float vi = wr * ai + wi * ar;
            const float ur = re[pos], ui = im[pos];
            re[pos] = ur + vr;          im[pos] = ui + vi;
            re[pos + half] = ur - vr;   im[pos + half] = ui - vi;
        }
        __syncthreads();
    }
    // X1 = (Z[k]+conj(Z[N-k]))/2, X2 = (Z[k]-conj(Z[N-k]))/(2i)
    float* row1 = xfT + (size_t)(b * DM + 2 * p) * L_;
    float* row2 = row1 + L_;
    for (int k = tid; k < 2048; k += 256) {
        const int nk = (2048 - k) & 2047;
        const float zr = re[k],  zi = im[k];
        const float qr = re[nk], qi = im[nk];
        const float e1r = zr + qr, e1i = zi - qi;
        const float e2r = zr - qr, e2i = zi + qi;
        row1[k] = 0.5f * sqrtf(e1r * e1r + e1i * e1i);
        row2[k] = 0.5f * sqrtf(e2r * e2r + e2i * e2i);
    }
}

// ============ K6: out_proj + LN + FFN + LN + CNN + head + partial sum ============
__global__ __launch_bounds__(256) void k_tail(
    const float* __restrict__ yg, const float* __restrict__ xfT,
    const float* __restrict__ out_w,
    const float* __restrict__ ln1_g, const float* __restrict__ ln1_b,
    const float* __restrict__ w1, const float* __restrict__ b1,
    const float* __restrict__ w2, const float* __restrict__ b2,
    const float* __restrict__ lng, const float* __restrict__ lnb,
    const float* __restrict__ cnn_w, const float* __restrict__ cnn_b,
    const float* __restrict__ l1w, const float* __restrict__ l1b,
    const float* __restrict__ l2w, const float* __restrict__ l2b,
    const float* __restrict__ l3w, const float* __restrict__ l3b,
    float* __restrict__ part)
{
    const int tid = threadIdx.x;
    const int b   = blockIdx.x >> 3;
    const int l   = ((blockIdx.x & 7) << 8) + tid;
    const int t   = b * L_ + l;

    float y[DI];
#pragma unroll
    for (int e = 0; e < DI; ++e) y[e] = yg[t * DI + e];

    float m[DM];
#pragma unroll
    for (int j = 0; j < DM; ++j) {
        float acc = 0.0f;
#pragma unroll
        for (int e = 0; e < DI; ++e) acc += y[e] * out_w[j * DI + e];
        m[j] = acc;
    }
    float mean = 0.0f;
#pragma unroll
    for (int j = 0; j < DM; ++j) mean += m[j];
    mean *= (1.0f / DM);
    float var = 0.0f;
#pragma unroll
    for (int j = 0; j < DM; ++j) { const float dv = m[j] - mean; var += dv * dv; }
    var *= (1.0f / DM);
    const float inv1 = rsqrtf(var + 1e-12f);
    float h[DM];
#pragma unroll
    for (int j = 0; j < DM; ++j) h[j] = (m[j] - mean) * inv1 * ln1_g[j] + ln1_b[j];

    float ff[4 * DM];
#pragma unroll
    for (int e = 0; e < 4 * DM; ++e) {
        float acc = b1[e];
#pragma unroll
        for (int j = 0; j < DM; ++j) acc += h[j] * w1[e * DM + j];
        ff[e] = geluf(acc);
    }
    float f2[DM];
#pragma unroll
    for (int j = 0; j < DM; ++j) {
        float acc = b2[j];
#pragma unroll
        for (int e = 0; e < 4 * DM; ++e) acc += ff[e] * w2[j * (4 * DM) + e];
        f2[j] = acc + h[j];
    }
    mean = 0.0f;
#pragma unroll
    for (int j = 0; j < DM; ++j) mean += f2[j];
    mean *= (1.0f / DM);
    var = 0.0f;
#pragma unroll
    for (int j = 0; j < DM; ++j) { const float dv = f2[j] - mean; var += dv * dv; }
    var *= (1.0f / DM);
    const float inv2 = rsqrtf(var + 1e-12f);
    float xm[DM];
#pragma unroll
    for (int j = 0; j < DM; ++j) xm[j] = (f2[j] - mean) * inv2 * lng[j] + lnb[j];

    float xfm[DM], xf0[DM], xfp[DM];
#pragma unroll
    for (int i = 0; i < DM; ++i) {
        const float* row = xfT + (size_t)(b * DM + i) * L_;
        xfm[i] = (l == 0)      ? 0.0f : row[l - 1];
        xf0[i] = row[l];
        xfp[i] = (l == L_ - 1) ? 0.0f : row[l + 1];
    }
    float xc[DM];
#pragma unroll
    for (int o = 0; o < DM; ++o) {
        float acc = cnn_b[o];
#pragma unroll
        for (int i = 0; i < DM; ++i) {
            const int wb = (o * DM + i) * 3;
            acc += xfm[i] * cnn_w[wb] + xf0[i] * cnn_w[wb + 1] + xfp[i] * cnn_w[wb + 2];
        }
        xc[o] = acc;
    }

    float o1[DM];
#pragma unroll
    for (int d = 0; d < DM; ++d) {
        float acc = l1b[d];
#pragma unroll
        for (int e = 0; e < DM; ++e) acc += xm[e] * l1w[d * (2 * DM) + e];
#pragma unroll
        for (int e = 0; e < DM; ++e) acc += xc[e] * l1w[d * (2 * DM) + DM + e];
        o1[d] = eluf(acc);
    }
    float o2[20];
#pragma unroll
    for (int e = 0; e < 20; ++e) {
        float acc = l2b[e];
#pragma unroll
        for (int d = 0; d < DM; ++d) acc += o1[d] * l2w[e * DM + d];
        o2[e] = acc;
    }
    float o3 = l3b[0];
#pragma unroll
    for (int e = 0; e < 20; ++e) o3 += o2[e] * l3w[e];

    __shared__ float sred[256];
    sred[tid] = o3;
    __syncthreads();
    for (int s = 128; s > 0; s >>= 1) {
        if (tid < s) sred[tid] += sred[tid + s];
        __syncthreads();
    }
    if (tid == 0) part[blockIdx.x] = sred[0];
}

// ============ K7: final per-batch mean + sigmoid ============
__global__ void k_final(const float* __restrict__ part, float* __restrict__ out)
{
    const int b = threadIdx.x;
    if (b < B_) {
        float s = 0.0f;
        for (int i = 0; i < 8; ++i) s += part[b * 8 + i];
        s *= (1.0f / (float)L_);
        out[b] = 1.0f / (1.0f + expf(-s));
    }
}

extern "C" void kernel_launch(void* const* d_in, const int* in_sizes, int n_in,
                              void* d_out, int out_size, void* d_ws, size_t ws_size,
                              hipStream_t stream)
{
    const float* x        = (const float*)d_in[0];
    const float* in_w     = (const float*)d_in[1];
    const float* conv_w   = (const float*)d_in[2];
    const float* conv_b   = (const float*)d_in[3];
    const float* xproj_w  = (const float*)d_in[4];
    const float* dt_w     = (const float*)d_in[5];
    const float* dt_b     = (const float*)d_in[6];
    const float* A_log    = (const float*)d_in[7];
    const float* Dp       = (const float*)d_in[8];
    const float* out_w    = (const float*)d_in[9];
    const float* ln1_g    = (const float*)d_in[10];
    const float* ln1_b    = (const float*)d_in[11];
    const float* ffn_w1   = (const float*)d_in[12];
    const float* ffn_b1   = (const float*)d_in[13];
    const float* ffn_w2   = (const float*)d_in[14];
    const float* ffn_b2   = (const float*)d_in[15];
    const float* ffn_ln_g = (const float*)d_in[16];
    const float* ffn_ln_b = (const float*)d_in[17];
    const float* cnn_w    = (const float*)d_in[18];
    const float* cnn_b    = (const float*)d_in[19];
    const float* l1w      = (const float*)d_in[20];
    const float* l1b      = (const float*)d_in[21];
    const float* l2w      = (const float*)d_in[22];
    const float* l2b      = (const float*)d_in[23];
    const float* l3w      = (const float*)d_in[24];
    const float* l3b      = (const float*)d_in[25];
    float* out = (float*)d_out;

    float* ws = (float*)d_ws;
    const size_t nTDI = (size_t)T_ * DI;
    const size_t nTDS = (size_t)T_ * DS;
    const size_t nU   = (size_t)B_ * DI * NCHUNK * DS;   // 786,432
    float* w_delta = ws;
    float* w_xi    = w_delta + nTDI;
    float* w_zs    = w_xi + nTDI;
    float* w_y     = w_zs + nTDI;
    float* w_Bm    = w_y + nTDI;
    float* w_Cm    = w_Bm + nTDS;
    float* w_P     = w_Cm + nTDS;
    float* w_H     = w_P + nU;
    float* w_H0    = w_H + nU;
    float* w_part  = w_H0 + nU;
    float* w_xfT   = w_P;          // alias: P+H (1,572,864 floats) dead after scan2

    k_proj<<<512, 256, 0, stream>>>(x, in_w, conv_w, conv_b, xproj_w, dt_w, dt_b,
                                    w_xi, w_zs, w_delta, w_Bm, w_Cm);
    k_scan1<<<B_ * (NCHUNK / CPB), 384, 0, stream>>>(w_delta, w_xi, w_Bm, A_log, w_P, w_H);
    k_scan2<<<96, 256, 0, stream>>>(w_P, w_H, w_H0);
    k_fft<<<B_ * (DM / 2), 256, 0, stream>>>(x, w_xfT);   // overwrites P,H (now dead)
    k_scan3<<<B_ * (NCHUNK / CPB), 384, 0, stream>>>(w_delta, w_xi, w_Bm, w_Cm, w_zs, Dp,
                                                     w_H0, A_log, w_y);
    k_tail<<<512, 256, 0, stream>>>(w_y, w_xfT, out_w,
                                    ln1_g, ln1_b, ffn_w1, ffn_b1, ffn_w2, ffn_b2,
                                    ffn_ln_g, ffn_ln_b, cnn_w, cnn_b,
                                    l1w, l1b, l2w, l2b, l3w, l3b, w_part);
    k_final<<<1, 64, 0, stream>>>(w_part, out);
}

// Round 6
// 183.504 us; speedup vs baseline: 1.5028x; 1.2006x over previous
//
#include <hip/hip_runtime.h>
#include <math.h>

#define B_  64
#define L_  2048
#define DM  12
#define DI  24
#define DS  16
#define DC  4
#define DTR 1
#define T_  (B_ * L_)        // 131072 tokens
#define NCHUNK 32
#define CHUNK  64            // L_ / NCHUNK

// ---------------- ws layout (floats) — identical to round 5 (passed) ----
// delta : T*DI   3,145,728
// xi    : T*DI   3,145,728
// zs    : T*DI   3,145,728
// y     : T*DI   3,145,728   (gated scan output, t-major)
// Bm    : T*DS   2,097,152
// Cm    : T*DS   2,097,152
// P     : B*DI*NCHUNK*DS   786,432   \ aliased as xf (B*DM*L = 1,572,864)
// H     : B*DI*NCHUNK*DS   786,432   /  after scan2 completes
// H0    : B*DI*NCHUNK*DS   786,432
// part  : 512

__device__ __forceinline__ float siluf(float v)  { return v / (1.0f + __expf(-v)); }
__device__ __forceinline__ float softplusf(float v) {
    if (v > 20.0f)  return v;
    if (v < -20.0f) return __expf(v);
    return __logf(1.0f + __expf(v));
}
__device__ __forceinline__ float geluf(float v) {
    return 0.5f * v * (1.0f + erff(v * 0.70710678118654752440f));
}
__device__ __forceinline__ float eluf(float v) { return v > 0.0f ? v : __expf(v) - 1.0f; }

// DPP lane-sum helpers: quad_perm{1,0,3,2}=0xB1 (xor1), quad_perm{2,3,0,1}=0x4E (xor2),
// row_half_mirror=0x141 (pairs the two quads of each 8-lane group once quads are uniform)
#define DPP_ADD(p, ctrl) \
    (p) += __int_as_float(__builtin_amdgcn_update_dpp(0, __float_as_int(p), (ctrl), 0xF, 0xF, true))

// ============ K1: in_proj + depthwise causal conv + silu + x_proj + delta ============
__global__ __launch_bounds__(256) void k_proj(
    const float* __restrict__ x, const float* __restrict__ w_in,
    const float* __restrict__ conv_w, const float* __restrict__ conv_b,
    const float* __restrict__ xproj_w, const float* __restrict__ dt_w,
    const float* __restrict__ dt_b,
    float* __restrict__ xi_out, float* __restrict__ zs_out,
    float* __restrict__ delta_out, float* __restrict__ Bm_out,
    float* __restrict__ Cm_out)
{
    __shared__ float s_xi[256 + 3][DI + 1];
    const int tid = threadIdx.x;
    const int b   = blockIdx.x >> 3;
    const int l0  = (blockIdx.x & 7) << 8;
    const int l   = l0 + tid;
    const int t   = b * L_ + l;

    float xv[DM];
    *(float4*)&xv[0] = *(const float4*)&x[t * DM + 0];
    *(float4*)&xv[4] = *(const float4*)&x[t * DM + 4];
    *(float4*)&xv[8] = *(const float4*)&x[t * DM + 8];

#pragma unroll
    for (int e = 0; e < DI; ++e) {
        float acc = 0.0f;
#pragma unroll
        for (int d = 0; d < DM; ++d) acc += xv[d] * w_in[(DI + e) * DM + d];
        zs_out[t * DI + e] = siluf(acc);
    }
#pragma unroll
    for (int e = 0; e < DI; ++e) {
        float acc = 0.0f;
#pragma unroll
        for (int d = 0; d < DM; ++d) acc += xv[d] * w_in[e * DM + d];
        s_xi[tid + 3][e] = acc;
    }
    if (tid < 3) {
        const int lh = l0 - 3 + tid;
        if (lh < 0) {
            for (int e = 0; e < DI; ++e) s_xi[tid][e] = 0.0f;
        } else {
            const int th = b * L_ + lh;
            float xh[DM];
            for (int d = 0; d < DM; ++d) xh[d] = x[th * DM + d];
            for (int e = 0; e < DI; ++e) {
                float acc = 0.0f;
                for (int d = 0; d < DM; ++d) acc += xh[d] * w_in[e * DM + d];
                s_xi[tid][e] = acc;
            }
        }
    }
    __syncthreads();

    float xi[DI];
#pragma unroll
    for (int dch = 0; dch < DI; ++dch) {
        float acc = conv_b[dch];
#pragma unroll
        for (int k = 0; k < DC; ++k) acc += s_xi[tid + k][dch] * conv_w[dch * DC + k];
        xi[dch] = siluf(acc);
        xi_out[t * DI + dch] = xi[dch];
    }

    float dt = 0.0f;
#pragma unroll
    for (int d = 0; d < DI; ++d) dt += xi[d] * xproj_w[d];
#pragma unroll
    for (int e = 0; e < DS; ++e) {
        float accB = 0.0f, accC = 0.0f;
#pragma unroll
        for (int d = 0; d < DI; ++d) {
            accB += xi[d] * xproj_w[(1 + e) * DI + d];
            accC += xi[d] * xproj_w[(1 + DS + e) * DI + d];
        }
        Bm_out[t * DS + e] = accB;
        Cm_out[t * DS + e] = accC;
    }
#pragma unroll
    for (int d = 0; d < DI; ++d)
        delta_out[t * DI + d] = softplusf(dt * dt_w[d] + dt_b[d]);
}

// ============ S1: local chunk scan — thread = (b,c,d,n-pair); 2 h's in regs ============
// 192 threads per chunk, 2 chunks per 384-block -> 1024 blocks, 6144 waves
__global__ __launch_bounds__(384) void k_scan1(
    const float* __restrict__ delta, const float* __restrict__ xi,
    const float* __restrict__ Bm, const float* __restrict__ A_log,
    float* __restrict__ P, float* __restrict__ H)
{
    const int tid = threadIdx.x;          // (cl*24 + d)*8 + q
    const int q   = tid & 7;
    const int g   = tid >> 3;
    const int d   = g % DI;
    const int cl  = g / DI;               // 0..1
    const int b   = blockIdx.x >> 4;      // 16 blocks per batch
    const int c   = ((blockIdx.x & 15) << 1) + cl;
    const int t0  = b * L_ + c * CHUNK;

    float An0 = -__expf(A_log[d * DS + 2 * q]);
    float An1 = -__expf(A_log[d * DS + 2 * q + 1]);
    float h0 = 0.0f, h1 = 0.0f, p0 = 1.0f, p1 = 1.0f;

    const float* pD = delta + (size_t)t0 * DI + d;
    const float* pX = xi    + (size_t)t0 * DI + d;
    const float* pB = Bm    + (size_t)t0 * DS + 2 * q;

#pragma unroll 4
    for (int i = 0; i < CHUNK; ++i) {
        const float del = pD[i * DI];
        const float u   = del * pX[i * DI];
        const float2 Bv = *(const float2*)&pB[i * DS];
        const float a0 = __expf(del * An0);
        h0 = a0 * h0 + u * Bv.x;
        p0 *= a0;
        const float a1 = __expf(del * An1);
        h1 = a1 * h1 + u * Bv.y;
        p1 *= a1;
    }
    const int u2 = ((b * DI + d) * NCHUNK + c) * DS + 2 * q;
    *(float2*)&P[u2] = make_float2(p0, p1);
    *(float2*)&H[u2] = make_float2(h0, h1);
}

// ============ S2: combine chunk summaries (thread = (b,d,n)) ============
__global__ __launch_bounds__(256) void k_scan2(
    const float* __restrict__ P, const float* __restrict__ H, float* __restrict__ H0)
{
    const int idx  = blockIdx.x * 256 + threadIdx.x;  // 24576 = (b*DI+d)*16 + n
    const int n    = idx & 15;
    const int rest = idx >> 4;
    float Hc = 0.0f;
    const int base = rest * NCHUNK * DS + n;
    for (int c = 0; c < NCHUNK; ++c) {
        const int u = base + c * DS;
        H0[u] = Hc;
        Hc = P[u] * Hc + H[u];
    }
}

// ============ S3: replay with h0 + fused gate, y stored t-major ============
__global__ __launch_bounds__(384) void k_scan3(
    const float* __restrict__ delta, const float* __restrict__ xi,
    const float* __restrict__ Bm, const float* __restrict__ Cm,
    const float* __restrict__ zs, const float* __restrict__ Dp,
    const float* __restrict__ H0, const float* __restrict__ A_log,
    float* __restrict__ y_out)
{
    const int tid = threadIdx.x;
    const int q   = tid & 7;
    const int g   = tid >> 3;
    const int d   = g % DI;
    const int cl  = g / DI;
    const int b   = blockIdx.x >> 4;
    const int c   = ((blockIdx.x & 15) << 1) + cl;
    const int t0  = b * L_ + c * CHUNK;

    const float An0 = -__expf(A_log[d * DS + 2 * q]);
    const float An1 = -__expf(A_log[d * DS + 2 * q + 1]);
    const float Dpd = Dp[d];

    const int u2 = ((b * DI + d) * NCHUNK + c) * DS + 2 * q;
    const float2 h0v = *(const float2*)&H0[u2];
    float h0 = h0v.x, h1 = h0v.y;

    const float* pD = delta + (size_t)t0 * DI + d;
    const float* pX = xi    + (size_t)t0 * DI + d;
    const float* pZ = zs    + (size_t)t0 * DI + d;
    const float* pB = Bm    + (size_t)t0 * DS + 2 * q;
    const float* pC = Cm    + (size_t)t0 * DS + 2 * q;
    float*       pY = y_out + (size_t)t0 * DI + d;

#pragma unroll 4
    for (int i = 0; i < CHUNK; ++i) {
        const float del = pD[i * DI];
        const float xiv = pX[i * DI];
        const float u   = del * xiv;
        const float2 Bv = *(const float2*)&pB[i * DS];
        const float2 Cv = *(const float2*)&pC[i * DS];
        const float a0 = __expf(del * An0);
        h0 = a0 * h0 + u * Bv.x;
        const float a1 = __expf(del * An1);
        h1 = a1 * h1 + u * Bv.y;
        float p = h0 * Cv.x + h1 * Cv.y;
        DPP_ADD(p, 0xB1);    // + lane^1
        DPP_ADD(p, 0x4E);    // + lane^2  (quads now uniform)
        DPP_ADD(p, 0x141);   // row_half_mirror: adds the other quad of the 8-group
        if (q == 0) pY[i * DI] = (p + xiv * Dpd) * pZ[i * DI];
    }
}

// ============ K5: two real FFTs per complex 2048-pt FFT, xfT (dm-major) out ============
__global__ __launch_bounds__(256) void k_fft(
    const float* __restrict__ x, float* __restrict__ xfT)
{
    __shared__ float re[2048], im[2048], twr[1024], twi[1024];
    const int tid = threadIdx.x;
    const int b   = blockIdx.x / (DM / 2);
    const int p   = blockIdx.x % (DM / 2);   // channel pair (2p, 2p+1)
    for (int j = tid; j < 1024; j += 256) {
        const float ang = -6.283185307179586f * (float)j * (1.0f / 2048.0f);
        float s, c;
        sincosf(ang, &s, &c);
        twr[j] = c; twi[j] = s;
    }
    for (int i = tid; i < 2048; i += 256) {
        const int r = (int)(__brev((unsigned)i) >> 21);
        const float2 v = *(const float2*)&x[(size_t)(b * L_ + i) * DM + 2 * p];
        re[r] = v.x;
        im[r] = v.y;
    }
    __syncthreads();
    for (int s = 1; s <= 11; ++s) {
        const int half  = 1 << (s - 1);
        const int tstep = 2048 >> s;
        for (int i = tid; i < 1024; i += 256) {
            const int j   = i & (half - 1);
            const int grp = i >> (s - 1);
            const int pos = (grp << s) + j;
            const float wr = twr[j * tstep], wi = twi[j * tstep];
            const float ar = re[pos + half], ai = im[pos + half];
            const float vr = wr * ar - wi * ai;
            const float vi = wr * ai + wi * ar;
            const float ur = re[pos], ui = im[pos];
            re[pos] = ur + vr;          im[pos] = ui + vi;
            re[pos + half] = ur - vr;   im[pos + half] = ui - vi;
        }
        __syncthreads();
    }
    // X1 = (Z[k]+conj(Z[N-k]))/2, X2 = (Z[k]-conj(Z[N-k]))/(2i)
    float* row1 = xfT + (size_t)(b * DM + 2 * p) * L_;
    float* row2 = row1 + L_;
    for (int k = tid; k < 2048; k += 256) {
        const int nk = (2048 - k) & 2047;
        const float zr = re[k],  zi = im[k];
        const float qr = re[nk], qi = im[nk];
        const float e1r = zr + qr, e1i = zi - qi;
        const float e2r = zr - qr, e2i = zi + qi;
        row1[k] = 0.5f * sqrtf(e1r * e1r + e1i * e1i);
        row2[k] = 0.5f * sqrtf(e2r * e2r + e2i * e2i);
    }
}

// ============ K6: out_proj + LN + FFN + LN + CNN + head + partial sum ============
__global__ __launch_bounds__(256) void k_tail(
    const float* __restrict__ yg, const float* __restrict__ xfT,
    const float* __restrict__ out_w,
    const float* __restrict__ ln1_g, const float* __restrict__ ln1_b,
    const float* __restrict__ w1, const float* __restrict__ b1,
    const float* __restrict__ w2, const float* __restrict__ b2,
    const float* __restrict__ lng, const float* __restrict__ lnb,
    const float* __restrict__ cnn_w, const float* __restrict__ cnn_b,
    const float* __restrict__ l1w, const float* __restrict__ l1b,
    const float* __restrict__ l2w, const float* __restrict__ l2b,
    const float* __restrict__ l3w, const float* __restrict__ l3b,
    float* __restrict__ part)
{
    const int tid = threadIdx.x;
    const int b   = blockIdx.x >> 3;
    const int l   = ((blockIdx.x & 7) << 8) + tid;
    const int t   = b * L_ + l;

    float y[DI];
#pragma unroll
    for (int e = 0; e < DI; ++e) y[e] = yg[t * DI + e];

    float m[DM];
#pragma unroll
    for (int j = 0; j < DM; ++j) {
        float acc = 0.0f;
#pragma unroll
        for (int e = 0; e < DI; ++e) acc += y[e] * out_w[j * DI + e];
        m[j] = acc;
    }
    float mean = 0.0f;
#pragma unroll
    for (int j = 0; j < DM; ++j) mean += m[j];
    mean *= (1.0f / DM);
    float var = 0.0f;
#pragma unroll
    for (int j = 0; j < DM; ++j) { const float dv = m[j] - mean; var += dv * dv; }
    var *= (1.0f / DM);
    const float inv1 = rsqrtf(var + 1e-12f);
    float h[DM];
#pragma unroll
    for (int j = 0; j < DM; ++j) h[j] = (m[j] - mean) * inv1 * ln1_g[j] + ln1_b[j];

    float ff[4 * DM];
#pragma unroll
    for (int e = 0; e < 4 * DM; ++e) {
        float acc = b1[e];
#pragma unroll
        for (int j = 0; j < DM; ++j) acc += h[j] * w1[e * DM + j];
        ff[e] = geluf(acc);
    }
    float f2[DM];
#pragma unroll
    for (int j = 0; j < DM; ++j) {
        float acc = b2[j];
#pragma unroll
        for (int e = 0; e < 4 * DM; ++e) acc += ff[e] * w2[j * (4 * DM) + e];
        f2[j] = acc + h[j];
    }
    mean = 0.0f;
#pragma unroll
    for (int j = 0; j < DM; ++j) mean += f2[j];
    mean *= (1.0f / DM);
    var = 0.0f;
#pragma unroll
    for (int j = 0; j < DM; ++j) { const float dv = f2[j] - mean; var += dv * dv; }
    var *= (1.0f / DM);
    const float inv2 = rsqrtf(var + 1e-12f);
    float xm[DM];
#pragma unroll
    for (int j = 0; j < DM; ++j) xm[j] = (f2[j] - mean) * inv2 * lng[j] + lnb[j];

    float xfm[DM], xf0[DM], xfp[DM];
#pragma unroll
    for (int i = 0; i < DM; ++i) {
        const float* row = xfT + (size_t)(b * DM + i) * L_;
        xfm[i] = (l == 0)      ? 0.0f : row[l - 1];
        xf0[i] = row[l];
        xfp[i] = (l == L_ - 1) ? 0.0f : row[l + 1];
    }
    float xc[DM];
#pragma unroll
    for (int o = 0; o < DM; ++o) {
        float acc = cnn_b[o];
#pragma unroll
        for (int i = 0; i < DM; ++i) {
            const int wb = (o * DM + i) * 3;
            acc += xfm[i] * cnn_w[wb] + xf0[i] * cnn_w[wb + 1] + xfp[i] * cnn_w[wb + 2];
        }
        xc[o] = acc;
    }

    float o1[DM];
#pragma unroll
    for (int d = 0; d < DM; ++d) {
        float acc = l1b[d];
#pragma unroll
        for (int e = 0; e < DM; ++e) acc += xm[e] * l1w[d * (2 * DM) + e];
#pragma unroll
        for (int e = 0; e < DM; ++e) acc += xc[e] * l1w[d * (2 * DM) + DM + e];
        o1[d] = eluf(acc);
    }
    float o2[20];
#pragma unroll
    for (int e = 0; e < 20; ++e) {
        float acc = l2b[e];
#pragma unroll
        for (int d = 0; d < DM; ++d) acc += o1[d] * l2w[e * DM + d];
        o2[e] = acc;
    }
    float o3 = l3b[0];
#pragma unroll
    for (int e = 0; e < 20; ++e) o3 += o2[e] * l3w[e];

    __shared__ float sred[256];
    sred[tid] = o3;
    __syncthreads();
    for (int s = 128; s > 0; s >>= 1) {
        if (tid < s) sred[tid] += sred[tid + s];
        __syncthreads();
    }
    if (tid == 0) part[blockIdx.x] = sred[0];
}

// ============ K7: final per-batch mean + sigmoid ============
__global__ void k_final(const float* __restrict__ part, float* __restrict__ out)
{
    const int b = threadIdx.x;
    if (b < B_) {
        float s = 0.0f;
        for (int i = 0; i < 8; ++i) s += part[b * 8 + i];
        s *= (1.0f / (float)L_);
        out[b] = 1.0f / (1.0f + __expf(-s));
    }
}

extern "C" void kernel_launch(void* const* d_in, const int* in_sizes, int n_in,
                              void* d_out, int out_size, void* d_ws, size_t ws_size,
                              hipStream_t stream)
{
    const float* x        = (const float*)d_in[0];
    const float* in_w     = (const float*)d_in[1];
    const float* conv_w   = (const float*)d_in[2];
    const float* conv_b   = (const float*)d_in[3];
    const float* xproj_w  = (const float*)d_in[4];
    const float* dt_w     = (const float*)d_in[5];
    const float* dt_b     = (const float*)d_in[6];
    const float* A_log    = (const float*)d_in[7];
    const float* Dp       = (const float*)d_in[8];
    const float* out_w    = (const float*)d_in[9];
    const float* ln1_g    = (const float*)d_in[10];
    const float* ln1_b    = (const float*)d_in[11];
    const float* ffn_w1   = (const float*)d_in[12];
    const float* ffn_b1   = (const float*)d_in[13];
    const float* ffn_w2   = (const float*)d_in[14];
    const float* ffn_b2   = (const float*)d_in[15];
    const float* ffn_ln_g = (const float*)d_in[16];
    const float* ffn_ln_b = (const float*)d_in[17];
    const float* cnn_w    = (const float*)d_in[18];
    const float* cnn_b    = (const float*)d_in[19];
    const float* l1w      = (const float*)d_in[20];
    const float* l1b      = (const float*)d_in[21];
    const float* l2w      = (const float*)d_in[22];
    const float* l2b      = (const float*)d_in[23];
    const float* l3w      = (const float*)d_in[24];
    const float* l3b      = (const float*)d_in[25];
    float* out = (float*)d_out;

    float* ws = (float*)d_ws;
    const size_t nTDI = (size_t)T_ * DI;
    const size_t nTDS = (size_t)T_ * DS;
    const size_t nU   = (size_t)B_ * DI * NCHUNK * DS;   // 786,432
    float* w_delta = ws;
    float* w_xi    = w_delta + nTDI;
    float* w_zs    = w_xi + nTDI;
    float* w_y     = w_zs + nTDI;
    float* w_Bm    = w_y + nTDI;
    float* w_Cm    = w_Bm + nTDS;
    float* w_P     = w_Cm + nTDS;
    float* w_H     = w_P + nU;
    float* w_H0    = w_H + nU;
    float* w_part  = w_H0 + nU;
    float* w_xfT   = w_P;          // alias: P+H (1,572,864 floats) dead after scan2

    k_proj<<<512, 256, 0, stream>>>(x, in_w, conv_w, conv_b, xproj_w, dt_w, dt_b,
                                    w_xi, w_zs, w_delta, w_Bm, w_Cm);
    k_scan1<<<B_ * (NCHUNK / 2), 384, 0, stream>>>(w_delta, w_xi, w_Bm, A_log, w_P, w_H);
    k_scan2<<<96, 256, 0, stream>>>(w_P, w_H, w_H0);
    k_fft<<<B_ * (DM / 2), 256, 0, stream>>>(x, w_xfT);   // overwrites P,H (now dead)
    k_scan3<<<B_ * (NCHUNK / 2), 384, 0, stream>>>(w_delta, w_xi, w_Bm, w_Cm, w_zs, Dp,
                                                   w_H0, A_log, w_y);
    k_tail<<<512, 256, 0, stream>>>(w_y, w_xfT, out_w,
                                    ln1_g, ln1_b, ffn_w1, ffn_b1, ffn_w2, ffn_b2,
                                    ffn_ln_g, ffn_ln_b, cnn_w, cnn_b,
                                    l1w, l1b, l2w, l2b, l3w, l3b, w_part);
    k_final<<<1, 64, 0, stream>>>(w_part, out);
}